// Round 3
// baseline (2886.778 us; speedup 1.0000x reference)
//
#include <hip/hip_runtime.h>
#include <math.h>

#define IN_CH 13
#define HIDDEN 20
#define NCLS 10
#define NBASIS 8
#define NGRID 12
#define NTHREADS 256
#define HSTRIDE 32   // floats per sample in h: 128 B = one cache line/sample

// All inputs/outputs are fp32 (verified: fp32 path passes with absmax=0.0).

// Support-restricted cubic B-spline: bit-identical to the full Cox-de Boor
// recursion (verified absmax=0.0 rounds 1-2), 12 divides instead of 54.
// Outputs 4 basis values for indices j0-3..j0 and clamped coefficient
// indices (clamped index <=> basis value is exactly +0).
__device__ inline void spline4(float xv, const float* __restrict__ g,
                               float& s0, float& s1, float& s2, float& s3,
                               int& m0, int& m1, int& m2, int& m3)
{
    int cnt = 0;
    #pragma unroll
    for (int j = 0; j < NGRID; ++j) cnt += (xv >= g[j]) ? 1 : 0;
    int j0 = cnt - 1;

    s0 = 0.f; s1 = 0.f; s2 = 0.f;
    s3 = (j0 >= 0 && j0 <= NGRID - 2) ? 1.f : 0.f;

    { // p = 1
        int j = j0 - 1;
        float v = 0.f;
        if (j >= 0 && j <= NGRID - 3)
            v = (g[j + 2] - xv) / (g[j + 2] - g[j + 1]) * s3;
        s2 = v;
        j = j0;
        v = 0.f;
        if (j >= 0 && j <= NGRID - 3)
            v = (xv - g[j]) / (g[j + 1] - g[j]) * s3;
        s3 = v;
    }
    { // p = 2
        int j = j0 - 2;
        float v = 0.f;
        if (j >= 0 && j <= NGRID - 4)
            v = (g[j + 3] - xv) / (g[j + 3] - g[j + 1]) * s2;
        s1 = v;
        j = j0 - 1;
        v = 0.f;
        if (j >= 0 && j <= NGRID - 4)
            v = (xv - g[j]) / (g[j + 2] - g[j]) * s2
              + (g[j + 3] - xv) / (g[j + 3] - g[j + 1]) * s3;
        s2 = v;
        j = j0;
        v = 0.f;
        if (j >= 0 && j <= NGRID - 4)
            v = (xv - g[j]) / (g[j + 2] - g[j]) * s3;
        s3 = v;
    }
    { // p = 3
        int j = j0 - 3;
        float v = 0.f;
        if (j >= 0 && j <= NGRID - 5)
            v = (g[j + 4] - xv) / (g[j + 4] - g[j + 1]) * s1;
        s0 = v;
        j = j0 - 2;
        v = 0.f;
        if (j >= 0 && j <= NGRID - 5)
            v = (xv - g[j]) / (g[j + 3] - g[j]) * s1
              + (g[j + 4] - xv) / (g[j + 4] - g[j + 1]) * s2;
        s1 = v;
        j = j0 - 1;
        v = 0.f;
        if (j >= 0 && j <= NGRID - 5)
            v = (xv - g[j]) / (g[j + 3] - g[j]) * s2
              + (g[j + 4] - xv) / (g[j + 4] - g[j + 1]) * s3;
        s2 = v;
        j = j0;
        v = 0.f;
        if (j >= 0 && j <= NGRID - 5)
            v = (xv - g[j]) / (g[j + 3] - g[j]) * s3;
        s3 = v;
    }

    m0 = j0 - 3; m1 = j0 - 2; m2 = j0 - 1; m3 = j0;
    m0 = m0 < 0 ? 0 : (m0 > NBASIS - 1 ? NBASIS - 1 : m0);
    m1 = m1 < 0 ? 0 : (m1 > NBASIS - 1 ? NBASIS - 1 : m1);
    m2 = m2 < 0 ? 0 : (m2 > NBASIS - 1 ? NBASIS - 1 : m2);
    m3 = m3 < 0 ? 0 : (m3 > NBASIS - 1 ? NBASIS - 1 : m3);
}

// depthwise 3x3 stride-2 pad-1 conv, compile-time sizes, relu epilogue.
// For every stage shape used here only the LOWER bound can fail.
template<int IW, int OW>
__device__ inline void dwconv3t(const float* __restrict__ in, float* __restrict__ out,
                                const float* __restrict__ w, float bias, int tid) {
    constexpr int N = OW * OW;
    constexpr int ITER = (N + NTHREADS - 1) / NTHREADS;
    #pragma unroll
    for (int r = 0; r < ITER; ++r) {
        int o = tid + r * NTHREADS;
        if (N >= NTHREADS || o < N) {
            int oy = o / OW, ox = o % OW;      // OW pow2 -> shifts/masks
            float acc = bias;
            #pragma unroll
            for (int ky = 0; ky < 3; ++ky) {
                int iy = 2 * oy - 1 + ky;
                bool yok = (iy >= 0);
                #pragma unroll
                for (int kx = 0; kx < 3; ++kx) {
                    int ix = 2 * ox - 1 + kx;
                    float v = (yok && ix >= 0) ? in[iy * IW + ix] : 0.0f;
                    acc = fmaf(w[ky * 3 + kx], v, acc);
                }
            }
            out[o] = fmaxf(acc, 0.0f);
        }
    }
}

// Fused conv pipeline + KAN head. The block that completes the 13th channel
// of a sample (device-scope counter) computes that sample's KAN head inline,
// overlapped with remaining conv blocks. Protocol (G12/G16):
//   writer: atomicExch(h) [device-coherent store] -> __threadfence [release]
//           -> atomicAdd(cnt)
//   reader: observe old==12 -> __syncthreads -> __threadfence [acquire /
//           cache-invalidate, all threads] -> volatile loads of h
__global__ __launch_bounds__(NTHREADS) void conv_kan(
    const float* __restrict__ x,
    const float* __restrict__ w1, const float* __restrict__ b1,
    const float* __restrict__ w2, const float* __restrict__ b2,
    const float* __restrict__ w3, const float* __restrict__ b3,
    const float* __restrict__ w4, const float* __restrict__ b4,
    const float* __restrict__ w5, const float* __restrict__ b5,
    const float* __restrict__ w6, const float* __restrict__ b6,
    const float* __restrict__ grid1, const float* __restrict__ coef1,
    const float* __restrict__ sb1,   const float* __restrict__ ss1,
    const float* __restrict__ bias1,
    const float* __restrict__ grid2, const float* __restrict__ coef2,
    const float* __restrict__ sb2,   const float* __restrict__ ss2,
    const float* __restrict__ bias2,
    float* __restrict__ h, int* __restrict__ cnt,
    float* __restrict__ out)
{
    __shared__ float sA[64 * 64];
    __shared__ float sB[32 * 32];
    __shared__ float sw[49];
    __shared__ float sbias[6];
    __shared__ int   sdone;
    // KAN scratch (finisher path only); ~1.2 KB extra LDS, still 7 blocks/CU
    __shared__ float kbase1[IN_CH];
    __shared__ float kbsp1[IN_CH * 4];
    __shared__ int   kn1[IN_CH * 4];
    __shared__ float kbase2[HIDDEN];
    __shared__ float kbsp2[HIDDEN * 4];
    __shared__ int   kn2[HIDDEN * 4];
    __shared__ float kz[NCLS];

    int tid = threadIdx.x;
    int bc = blockIdx.x;              // b*13 + c
    int c = bc % IN_CH;
    int b = bc / IN_CH;

    if (tid < 9) {
        sw[tid]      = w1[c * 9 + tid];
        sw[9 + tid]  = w2[c * 9 + tid];
        sw[18 + tid] = w3[c * 9 + tid];
        sw[27 + tid] = w4[c * 9 + tid];
        sw[36 + tid] = w5[c * 9 + tid];
    }
    if (tid < 4) sw[45 + tid] = w6[c * 4 + tid];
    if (tid == 0) {
        sbias[0] = b1[c]; sbias[1] = b2[c]; sbias[2] = b3[c];
        sbias[3] = b4[c]; sbias[4] = b5[c]; sbias[5] = b6[c];
    }

    const float4* xv = reinterpret_cast<const float4*>(x + (size_t)bc * 4096);
    float4* sAv = reinterpret_cast<float4*>(sA);
    #pragma unroll
    for (int i = 0; i < 4; ++i) {
        int v = tid + i * NTHREADS;
        sAv[v] = xv[v];
    }
    __syncthreads();

    dwconv3t<64, 32>(sA, sB, sw,      sbias[0], tid); __syncthreads();
    dwconv3t<32, 16>(sB, sA, sw + 9,  sbias[1], tid); __syncthreads();
    dwconv3t<16,  8>(sA, sB, sw + 18, sbias[2], tid); __syncthreads();
    dwconv3t< 8,  4>(sB, sA, sw + 27, sbias[3], tid); __syncthreads();
    dwconv3t< 4,  2>(sA, sB, sw + 36, sbias[4], tid); __syncthreads();

    if (tid == 0) {
        // conv6: 2x2 kernel, stride 1, no pad, no relu
        float acc = sbias[5]
                  + sw[45] * sB[0] + sw[46] * sB[1]
                  + sw[47] * sB[2] + sw[48] * sB[3];
        atomicExch(&h[(size_t)b * HSTRIDE + c], acc);  // device-coherent store
        __threadfence();                               // release
        int old = atomicAdd(&cnt[b], 1);
        sdone = (old == IN_CH - 1) ? 1 : 0;
    }
    __syncthreads();
    if (!sdone) return;

    // ---- finisher: KAN head for sample b ----
    __threadfence();   // acquire: invalidate stale cache copies of h

    // phase A: 13 threads, one input feature each: silu + spline -> LDS
    if (tid < IN_CH) {
        float xvv = ((volatile const float*)h)[(size_t)b * HSTRIDE + tid];
        kbase1[tid] = xvv / (1.0f + expf(-xvv));       // silu, identical expr
        float s0, s1, s2, s3; int m0, m1, m2, m3;
        spline4(xvv, grid1 + tid * NGRID, s0, s1, s2, s3, m0, m1, m2, m3);
        kbsp1[tid * 4 + 0] = s0; kbsp1[tid * 4 + 1] = s1;
        kbsp1[tid * 4 + 2] = s2; kbsp1[tid * 4 + 3] = s3;
        kn1[tid * 4 + 0] = m0; kn1[tid * 4 + 1] = m1;
        kn1[tid * 4 + 2] = m2; kn1[tid * 4 + 3] = m3;
    }
    __syncthreads();

    // phase B+C: 20 threads, one hidden unit each: layer-1 dot (exact
    // reference order: bias + sum_i in order), then silu + spline of it
    if (tid < HIDDEN) {
        float acc = bias1[tid];
        #pragma unroll 4
        for (int i = 0; i < IN_CH; ++i) {
            const float* cf = coef1 + (i * HIDDEN + tid) * NBASIS;
            float sp = kbsp1[i * 4 + 0] * cf[kn1[i * 4 + 0]]
                     + kbsp1[i * 4 + 1] * cf[kn1[i * 4 + 1]]
                     + kbsp1[i * 4 + 2] * cf[kn1[i * 4 + 2]]
                     + kbsp1[i * 4 + 3] * cf[kn1[i * 4 + 3]];
            acc += kbase1[i] * sb1[i * HIDDEN + tid] + sp * ss1[i * HIDDEN + tid];
        }
        float xvv = acc;
        kbase2[tid] = xvv / (1.0f + expf(-xvv));
        float s0, s1, s2, s3; int m0, m1, m2, m3;
        spline4(xvv, grid2 + tid * NGRID, s0, s1, s2, s3, m0, m1, m2, m3);
        kbsp2[tid * 4 + 0] = s0; kbsp2[tid * 4 + 1] = s1;
        kbsp2[tid * 4 + 2] = s2; kbsp2[tid * 4 + 3] = s3;
        kn2[tid * 4 + 0] = m0; kn2[tid * 4 + 1] = m1;
        kn2[tid * 4 + 2] = m2; kn2[tid * 4 + 3] = m3;
    }
    __syncthreads();

    // phase D: 10 threads, one class each: layer-2 dot in reference order
    if (tid < NCLS) {
        float acc = bias2[tid];
        #pragma unroll 4
        for (int i = 0; i < HIDDEN; ++i) {
            const float* cf = coef2 + (i * NCLS + tid) * NBASIS;
            float sp = kbsp2[i * 4 + 0] * cf[kn2[i * 4 + 0]]
                     + kbsp2[i * 4 + 1] * cf[kn2[i * 4 + 1]]
                     + kbsp2[i * 4 + 2] * cf[kn2[i * 4 + 2]]
                     + kbsp2[i * 4 + 3] * cf[kn2[i * 4 + 3]];
            acc += kbase2[i] * sb2[i * NCLS + tid] + sp * ss2[i * NCLS + tid];
        }
        kz[tid] = acc;
    }
    __syncthreads();

    // phase E: log_softmax, redundant per thread in fixed reference order
    if (tid < NCLS) {
        float m = kz[0];
        #pragma unroll
        for (int o = 1; o < NCLS; ++o) m = fmaxf(m, kz[o]);
        float sum = 0.0f;
        #pragma unroll
        for (int o = 0; o < NCLS; ++o) sum += expf(kz[o] - m);
        float lse = logf(sum) + m;
        out[(size_t)b * NCLS + tid] = kz[tid] - lse;
    }
}

extern "C" void kernel_launch(void* const* d_in, const int* in_sizes, int n_in,
                              void* d_out, int out_size, void* d_ws, size_t ws_size,
                              hipStream_t stream) {
    const float* x  = (const float*)d_in[0];
    const float* w1 = (const float*)d_in[1];  const float* b1 = (const float*)d_in[2];
    const float* w2 = (const float*)d_in[3];  const float* b2 = (const float*)d_in[4];
    const float* w3 = (const float*)d_in[5];  const float* b3 = (const float*)d_in[6];
    const float* w4 = (const float*)d_in[7];  const float* b4 = (const float*)d_in[8];
    const float* w5 = (const float*)d_in[9];  const float* b5 = (const float*)d_in[10];
    const float* w6 = (const float*)d_in[11]; const float* b6 = (const float*)d_in[12];
    const float* grid1 = (const float*)d_in[13];
    const float* coef1 = (const float*)d_in[14];
    const float* sb1   = (const float*)d_in[15];
    const float* ss1   = (const float*)d_in[16];
    const float* bias1 = (const float*)d_in[17];
    const float* grid2 = (const float*)d_in[18];
    const float* coef2 = (const float*)d_in[19];
    const float* sb2   = (const float*)d_in[20];
    const float* ss2   = (const float*)d_in[21];
    const float* bias2 = (const float*)d_in[22];

    int B = in_sizes[0] / (IN_CH * 64 * 64);     // 2048
    float* h = (float*)d_ws;                      // B * HSTRIDE fp32 (262 KB)
    int* cnt = (int*)((char*)d_ws + (size_t)B * HSTRIDE * sizeof(float));

    hipMemsetAsync(cnt, 0, (size_t)B * sizeof(int), stream);

    conv_kan<<<B * IN_CH, NTHREADS, 0, stream>>>(
        x, w1, b1, w2, b2, w3, b3, w4, b4, w5, b5, w6, b6,
        grid1, coef1, sb1, ss1, bias1,
        grid2, coef2, sb2, ss2, bias2,
        h, cnt, (float*)d_out);
}

// Round 4
// 605.284 us; speedup vs baseline: 4.7693x; 4.7693x over previous
//
#include <hip/hip_runtime.h>
#include <math.h>

#define IN_CH 13
#define HIDDEN 20
#define NCLS 10
#define NBASIS 8
#define NGRID 12
#define NTHREADS 256
#define KAN_BS 64

// All inputs/outputs are fp32 (verified: fp32 path passes with absmax=0.0).
//
// Round-3 lesson: fusing the KAN head into the conv kernel via device-scope
// atomics + __threadfence cost 36x (each per-block fence = L2 wb/inv on
// gfx950; 26k of them serialize the chip). Two stream-ordered kernels need
// no fences: kernel boundary provides visibility.

// Support-restricted cubic B-spline: bit-identical to the full Cox-de Boor
// recursion (verified absmax=0.0 rounds 1-3), 12 divides instead of 54.
// Outputs 4 basis values for indices j0-3..j0 and clamped coefficient
// indices (clamped index <=> basis value is exactly +0).
__device__ inline void spline4(float xv, const float* __restrict__ g,
                               float& s0, float& s1, float& s2, float& s3,
                               int& m0, int& m1, int& m2, int& m3)
{
    int cnt = 0;
    #pragma unroll
    for (int j = 0; j < NGRID; ++j) cnt += (xv >= g[j]) ? 1 : 0;
    int j0 = cnt - 1;

    s0 = 0.f; s1 = 0.f; s2 = 0.f;
    s3 = (j0 >= 0 && j0 <= NGRID - 2) ? 1.f : 0.f;

    { // p = 1
        int j = j0 - 1;
        float v = 0.f;
        if (j >= 0 && j <= NGRID - 3)
            v = (g[j + 2] - xv) / (g[j + 2] - g[j + 1]) * s3;
        s2 = v;
        j = j0;
        v = 0.f;
        if (j >= 0 && j <= NGRID - 3)
            v = (xv - g[j]) / (g[j + 1] - g[j]) * s3;
        s3 = v;
    }
    { // p = 2
        int j = j0 - 2;
        float v = 0.f;
        if (j >= 0 && j <= NGRID - 4)
            v = (g[j + 3] - xv) / (g[j + 3] - g[j + 1]) * s2;
        s1 = v;
        j = j0 - 1;
        v = 0.f;
        if (j >= 0 && j <= NGRID - 4)
            v = (xv - g[j]) / (g[j + 2] - g[j]) * s2
              + (g[j + 3] - xv) / (g[j + 3] - g[j + 1]) * s3;
        s2 = v;
        j = j0;
        v = 0.f;
        if (j >= 0 && j <= NGRID - 4)
            v = (xv - g[j]) / (g[j + 2] - g[j]) * s3;
        s3 = v;
    }
    { // p = 3
        int j = j0 - 3;
        float v = 0.f;
        if (j >= 0 && j <= NGRID - 5)
            v = (g[j + 4] - xv) / (g[j + 4] - g[j + 1]) * s1;
        s0 = v;
        j = j0 - 2;
        v = 0.f;
        if (j >= 0 && j <= NGRID - 5)
            v = (xv - g[j]) / (g[j + 3] - g[j]) * s1
              + (g[j + 4] - xv) / (g[j + 4] - g[j + 1]) * s2;
        s1 = v;
        j = j0 - 1;
        v = 0.f;
        if (j >= 0 && j <= NGRID - 5)
            v = (xv - g[j]) / (g[j + 3] - g[j]) * s2
              + (g[j + 4] - xv) / (g[j + 4] - g[j + 1]) * s3;
        s2 = v;
        j = j0;
        v = 0.f;
        if (j >= 0 && j <= NGRID - 5)
            v = (xv - g[j]) / (g[j + 3] - g[j]) * s3;
        s3 = v;
    }

    m0 = j0 - 3; m1 = j0 - 2; m2 = j0 - 1; m3 = j0;
    m0 = m0 < 0 ? 0 : (m0 > NBASIS - 1 ? NBASIS - 1 : m0);
    m1 = m1 < 0 ? 0 : (m1 > NBASIS - 1 ? NBASIS - 1 : m1);
    m2 = m2 < 0 ? 0 : (m2 > NBASIS - 1 ? NBASIS - 1 : m2);
    m3 = m3 < 0 ? 0 : (m3 > NBASIS - 1 ? NBASIS - 1 : m3);
}

// depthwise 3x3 stride-2 pad-1 conv, compile-time sizes, relu epilogue.
// For every stage shape used here only the LOWER bound can fail.
template<int IW, int OW>
__device__ inline void dwconv3t(const float* __restrict__ in, float* __restrict__ out,
                                const float* __restrict__ w, float bias, int tid) {
    constexpr int N = OW * OW;
    constexpr int ITER = (N + NTHREADS - 1) / NTHREADS;
    #pragma unroll
    for (int r = 0; r < ITER; ++r) {
        int o = tid + r * NTHREADS;
        if (N >= NTHREADS || o < N) {
            int oy = o / OW, ox = o % OW;      // OW pow2 -> shifts/masks
            float acc = bias;
            #pragma unroll
            for (int ky = 0; ky < 3; ++ky) {
                int iy = 2 * oy - 1 + ky;
                bool yok = (iy >= 0);
                #pragma unroll
                for (int kx = 0; kx < 3; ++kx) {
                    int ix = 2 * ox - 1 + kx;
                    float v = (yok && ix >= 0) ? in[iy * IW + ix] : 0.0f;
                    acc = fmaf(w[ky * 3 + kx], v, acc);
                }
            }
            out[o] = fmaxf(acc, 0.0f);
        }
    }
}

__global__ __launch_bounds__(NTHREADS) void conv_pipeline(
    const float* __restrict__ x,
    const float* __restrict__ w1, const float* __restrict__ b1,
    const float* __restrict__ w2, const float* __restrict__ b2,
    const float* __restrict__ w3, const float* __restrict__ b3,
    const float* __restrict__ w4, const float* __restrict__ b4,
    const float* __restrict__ w5, const float* __restrict__ b5,
    const float* __restrict__ w6, const float* __restrict__ b6,
    float* __restrict__ h)
{
    __shared__ float sA[64 * 64];
    __shared__ float sB[32 * 32];
    __shared__ float sw[49];
    __shared__ float sbias[6];

    int tid = threadIdx.x;
    int bc = blockIdx.x;              // b*13 + c
    int c = bc % IN_CH;

    if (tid < 9) {
        sw[tid]      = w1[c * 9 + tid];
        sw[9 + tid]  = w2[c * 9 + tid];
        sw[18 + tid] = w3[c * 9 + tid];
        sw[27 + tid] = w4[c * 9 + tid];
        sw[36 + tid] = w5[c * 9 + tid];
    }
    if (tid < 4) sw[45 + tid] = w6[c * 4 + tid];
    if (tid == 0) {
        sbias[0] = b1[c]; sbias[1] = b2[c]; sbias[2] = b3[c];
        sbias[3] = b4[c]; sbias[4] = b5[c]; sbias[5] = b6[c];
    }

    const float4* xv = reinterpret_cast<const float4*>(x + (size_t)bc * 4096);
    float4* sAv = reinterpret_cast<float4*>(sA);
    #pragma unroll
    for (int i = 0; i < 4; ++i) {
        int v = tid + i * NTHREADS;
        sAv[v] = xv[v];
    }
    __syncthreads();

    dwconv3t<64, 32>(sA, sB, sw,      sbias[0], tid); __syncthreads();
    dwconv3t<32, 16>(sB, sA, sw + 9,  sbias[1], tid); __syncthreads();
    dwconv3t<16,  8>(sA, sB, sw + 18, sbias[2], tid); __syncthreads();
    dwconv3t< 8,  4>(sB, sA, sw + 27, sbias[3], tid); __syncthreads();
    dwconv3t< 4,  2>(sA, sB, sw + 36, sbias[4], tid); __syncthreads();

    if (tid == 0) {
        // conv6: 2x2 kernel, stride 1, no pad, no relu
        float acc = sbias[5]
                  + sw[45] * sB[0] + sw[46] * sB[1]
                  + sw[47] * sB[2] + sw[48] * sB[3];
        h[bc] = acc;
    }
}

// Phase-parallel KAN head, one sample per 64-thread block (verified bit-exact
// as round-3's finisher path, absmax=0.0). Params read directly from global:
// 2048 blocks re-read the same ~20 KB -> L2/L3-hot, no LDS staging tail.
// Phase A: 13 threads (one input each): silu + spline -> LDS
// Phase B: 20 threads (one hidden unit each): layer-1 dot in reference
//          order, then silu + spline of the result
// Phase D: 10 threads (one class each): layer-2 dot in reference order
// Phase E: log_softmax, redundant per thread in fixed reference order
__global__ __launch_bounds__(KAN_BS) void kan_head(
    const float* __restrict__ h,
    const float* __restrict__ grid1, const float* __restrict__ coef1,
    const float* __restrict__ sb1,   const float* __restrict__ ss1,
    const float* __restrict__ bias1,
    const float* __restrict__ grid2, const float* __restrict__ coef2,
    const float* __restrict__ sb2,   const float* __restrict__ ss2,
    const float* __restrict__ bias2,
    float* __restrict__ out, int nsamples)
{
    __shared__ float kbase1[IN_CH];
    __shared__ float kbsp1[IN_CH * 4];
    __shared__ int   kn1[IN_CH * 4];
    __shared__ float kbase2[HIDDEN];
    __shared__ float kbsp2[HIDDEN * 4];
    __shared__ int   kn2[HIDDEN * 4];
    __shared__ float kz[NCLS];

    int tid = threadIdx.x;
    int b = blockIdx.x;
    if (b >= nsamples) return;

    // phase A
    if (tid < IN_CH) {
        float xvv = h[(size_t)b * IN_CH + tid];
        kbase1[tid] = xvv / (1.0f + expf(-xvv));       // silu, identical expr
        float s0, s1, s2, s3; int m0, m1, m2, m3;
        spline4(xvv, grid1 + tid * NGRID, s0, s1, s2, s3, m0, m1, m2, m3);
        kbsp1[tid * 4 + 0] = s0; kbsp1[tid * 4 + 1] = s1;
        kbsp1[tid * 4 + 2] = s2; kbsp1[tid * 4 + 3] = s3;
        kn1[tid * 4 + 0] = m0; kn1[tid * 4 + 1] = m1;
        kn1[tid * 4 + 2] = m2; kn1[tid * 4 + 3] = m3;
    }
    __syncthreads();

    // phase B: layer-1 dot (exact reference order: bias + sum_i in order),
    // then silu + spline of it
    if (tid < HIDDEN) {
        float acc = bias1[tid];
        #pragma unroll 4
        for (int i = 0; i < IN_CH; ++i) {
            const float* cf = coef1 + (i * HIDDEN + tid) * NBASIS;
            float sp = kbsp1[i * 4 + 0] * cf[kn1[i * 4 + 0]]
                     + kbsp1[i * 4 + 1] * cf[kn1[i * 4 + 1]]
                     + kbsp1[i * 4 + 2] * cf[kn1[i * 4 + 2]]
                     + kbsp1[i * 4 + 3] * cf[kn1[i * 4 + 3]];
            acc += kbase1[i] * sb1[i * HIDDEN + tid] + sp * ss1[i * HIDDEN + tid];
        }
        float xvv = acc;
        kbase2[tid] = xvv / (1.0f + expf(-xvv));
        float s0, s1, s2, s3; int m0, m1, m2, m3;
        spline4(xvv, grid2 + tid * NGRID, s0, s1, s2, s3, m0, m1, m2, m3);
        kbsp2[tid * 4 + 0] = s0; kbsp2[tid * 4 + 1] = s1;
        kbsp2[tid * 4 + 2] = s2; kbsp2[tid * 4 + 3] = s3;
        kn2[tid * 4 + 0] = m0; kn2[tid * 4 + 1] = m1;
        kn2[tid * 4 + 2] = m2; kn2[tid * 4 + 3] = m3;
    }
    __syncthreads();

    // phase D: layer-2 dot in reference order
    if (tid < NCLS) {
        float acc = bias2[tid];
        #pragma unroll 4
        for (int i = 0; i < HIDDEN; ++i) {
            const float* cf = coef2 + (i * NCLS + tid) * NBASIS;
            float sp = kbsp2[i * 4 + 0] * cf[kn2[i * 4 + 0]]
                     + kbsp2[i * 4 + 1] * cf[kn2[i * 4 + 1]]
                     + kbsp2[i * 4 + 2] * cf[kn2[i * 4 + 2]]
                     + kbsp2[i * 4 + 3] * cf[kn2[i * 4 + 3]];
            acc += kbase2[i] * sb2[i * NCLS + tid] + sp * ss2[i * NCLS + tid];
        }
        kz[tid] = acc;
    }
    __syncthreads();

    // phase E: log_softmax, redundant per thread in fixed reference order
    if (tid < NCLS) {
        float m = kz[0];
        #pragma unroll
        for (int o = 1; o < NCLS; ++o) m = fmaxf(m, kz[o]);
        float sum = 0.0f;
        #pragma unroll
        for (int o = 0; o < NCLS; ++o) sum += expf(kz[o] - m);
        float lse = logf(sum) + m;
        out[(size_t)b * NCLS + tid] = kz[tid] - lse;
    }
}

extern "C" void kernel_launch(void* const* d_in, const int* in_sizes, int n_in,
                              void* d_out, int out_size, void* d_ws, size_t ws_size,
                              hipStream_t stream) {
    const float* x  = (const float*)d_in[0];
    const float* w1 = (const float*)d_in[1];  const float* b1 = (const float*)d_in[2];
    const float* w2 = (const float*)d_in[3];  const float* b2 = (const float*)d_in[4];
    const float* w3 = (const float*)d_in[5];  const float* b3 = (const float*)d_in[6];
    const float* w4 = (const float*)d_in[7];  const float* b4 = (const float*)d_in[8];
    const float* w5 = (const float*)d_in[9];  const float* b5 = (const float*)d_in[10];
    const float* w6 = (const float*)d_in[11]; const float* b6 = (const float*)d_in[12];
    const float* grid1 = (const float*)d_in[13];
    const float* coef1 = (const float*)d_in[14];
    const float* sb1   = (const float*)d_in[15];
    const float* ss1   = (const float*)d_in[16];
    const float* bias1 = (const float*)d_in[17];
    const float* grid2 = (const float*)d_in[18];
    const float* coef2 = (const float*)d_in[19];
    const float* sb2   = (const float*)d_in[20];
    const float* ss2   = (const float*)d_in[21];
    const float* bias2 = (const float*)d_in[22];

    int B = in_sizes[0] / (IN_CH * 64 * 64);     // 2048
    float* h = (float*)d_ws;                      // B*IN_CH fp32

    conv_pipeline<<<B * IN_CH, NTHREADS, 0, stream>>>(
        x, w1, b1, w2, b2, w3, b3, w4, b4, w5, b5, w6, b6, h);

    kan_head<<<B, KAN_BS, 0, stream>>>(
        h, grid1, coef1, sb1, ss1, bias1, grid2, coef2, sb2, ss2, bias2,
        (float*)d_out, B);
}